// Round 1
// baseline (1375.958 us; speedup 1.0000x reference)
//
#include <hip/hip_runtime.h>

#define NN 50000      // nodes
#define NE 160000     // graph edges
#define NP 100000     // pos (=neg) edges
#define DIN 512
#define DH  256
#define DO  64

// ---------------- degree ----------------
__global__ __launch_bounds__(256) void deg_kernel(const int* __restrict__ dst, float* __restrict__ deg) {
    int e = blockIdx.x * 256 + threadIdx.x;
    if (e < NE) atomicAdd(&deg[dst[e]], 1.0f);
}

// ---------------- fp32 SGEMM, BM=BN=128, BK=16, 8x8 per thread ----------------
__global__ __launch_bounds__(256) void sgemm128(
    const float* __restrict__ A, const float* __restrict__ B, float* __restrict__ C,
    int M, int N, int K)
{
    __shared__ float As[16][128];
    __shared__ float Bs[16][128];
    const int tid = threadIdx.x;
    const int tx = tid & 15, ty = tid >> 4;
    const int row0 = blockIdx.y * 128, col0 = blockIdx.x * 128;

    float acc[8][8];
    #pragma unroll
    for (int i = 0; i < 8; ++i)
        #pragma unroll
        for (int j = 0; j < 8; ++j) acc[i][j] = 0.0f;

    for (int k0 = 0; k0 < K; k0 += 16) {
        __syncthreads();
        #pragma unroll
        for (int u = 0; u < 2; ++u) {
            int f4 = tid * 2 + u;            // 0..511
            int arow = f4 >> 2, ac4 = f4 & 3;
            float4 v = make_float4(0.f, 0.f, 0.f, 0.f);
            int r = row0 + arow;
            if (r < M) v = *(const float4*)&A[(size_t)r * K + k0 + ac4 * 4];
            As[ac4 * 4 + 0][arow] = v.x;
            As[ac4 * 4 + 1][arow] = v.y;
            As[ac4 * 4 + 2][arow] = v.z;
            As[ac4 * 4 + 3][arow] = v.w;
            int brow = f4 >> 5, bc4 = f4 & 31;
            float4 w = *(const float4*)&B[(size_t)(k0 + brow) * N + col0 + bc4 * 4];
            *(float4*)&Bs[brow][bc4 * 4] = w;
        }
        __syncthreads();
        #pragma unroll
        for (int kk = 0; kk < 16; ++kk) {
            float a[8], b[8];
            *(float4*)&a[0] = *(const float4*)&As[kk][ty * 8];
            *(float4*)&a[4] = *(const float4*)&As[kk][ty * 8 + 4];
            *(float4*)&b[0] = *(const float4*)&Bs[kk][tx * 8];
            *(float4*)&b[4] = *(const float4*)&Bs[kk][tx * 8 + 4];
            #pragma unroll
            for (int i = 0; i < 8; ++i)
                #pragma unroll
                for (int j = 0; j < 8; ++j)
                    acc[i][j] = fmaf(a[i], b[j], acc[i][j]);
        }
    }
    #pragma unroll
    for (int i = 0; i < 8; ++i) {
        int r = row0 + ty * 8 + i;
        if (r < M) {
            *(float4*)&C[(size_t)r * N + col0 + tx * 8]     = make_float4(acc[i][0], acc[i][1], acc[i][2], acc[i][3]);
            *(float4*)&C[(size_t)r * N + col0 + tx * 8 + 4] = make_float4(acc[i][4], acc[i][5], acc[i][6], acc[i][7]);
        }
    }
}

// ---------------- fp32 SGEMM, BM=BN=64, BK=16, 4x4 per thread (layer 2, N=64) ----
__global__ __launch_bounds__(256) void sgemm64(
    const float* __restrict__ A, const float* __restrict__ B, float* __restrict__ C,
    int M, int N, int K)
{
    __shared__ float As[16][64];
    __shared__ float Bs[16][64];
    const int tid = threadIdx.x;
    const int tx = tid & 15, ty = tid >> 4;
    const int row0 = blockIdx.y * 64, col0 = blockIdx.x * 64;

    float acc[4][4];
    #pragma unroll
    for (int i = 0; i < 4; ++i)
        #pragma unroll
        for (int j = 0; j < 4; ++j) acc[i][j] = 0.0f;

    for (int k0 = 0; k0 < K; k0 += 16) {
        __syncthreads();
        {
            int arow = tid >> 2, ac4 = tid & 3;
            float4 v = make_float4(0.f, 0.f, 0.f, 0.f);
            int r = row0 + arow;
            if (r < M) v = *(const float4*)&A[(size_t)r * K + k0 + ac4 * 4];
            As[ac4 * 4 + 0][arow] = v.x;
            As[ac4 * 4 + 1][arow] = v.y;
            As[ac4 * 4 + 2][arow] = v.z;
            As[ac4 * 4 + 3][arow] = v.w;
            int brow = tid >> 4, bc4 = tid & 15;
            float4 w = *(const float4*)&B[(size_t)(k0 + brow) * N + col0 + bc4 * 4];
            *(float4*)&Bs[brow][bc4 * 4] = w;
        }
        __syncthreads();
        #pragma unroll
        for (int kk = 0; kk < 16; ++kk) {
            float a[4], b[4];
            *(float4*)&a[0] = *(const float4*)&As[kk][ty * 4];
            *(float4*)&b[0] = *(const float4*)&Bs[kk][tx * 4];
            #pragma unroll
            for (int i = 0; i < 4; ++i)
                #pragma unroll
                for (int j = 0; j < 4; ++j)
                    acc[i][j] = fmaf(a[i], b[j], acc[i][j]);
        }
    }
    #pragma unroll
    for (int i = 0; i < 4; ++i) {
        int r = row0 + ty * 4 + i;
        if (r < M)
            *(float4*)&C[(size_t)r * N + col0 + tx * 4] = make_float4(acc[i][0], acc[i][1], acc[i][2], acc[i][3]);
    }
}

// ---------------- scatter-add (mean aggregation numerator) ----------------
// one float4 per thread; NF4 = feats/4 per node
template<int NF4>
__global__ __launch_bounds__(256) void scatter_kernel(
    const float* __restrict__ V, const int* __restrict__ src, const int* __restrict__ dst,
    float* __restrict__ AGG)
{
    int idx = blockIdx.x * 256 + threadIdx.x;
    if (idx >= NE * NF4) return;
    int e = idx / NF4;
    int q = idx - e * NF4;
    int s = src[e], d = dst[e];
    float4 v = ((const float4*)V)[(size_t)s * NF4 + q];
    float* p = &AGG[((size_t)d * NF4 + q) * 4];
    atomicAdd(p + 0, v.x);
    atomicAdd(p + 1, v.y);
    atomicAdd(p + 2, v.z);
    atomicAdd(p + 3, v.w);
}

// ---------------- combine: H = (relu?)(S + AGG/deg + b) ----------------
template<int NF4, bool RELU>
__global__ __launch_bounds__(256) void combine_kernel(
    const float* __restrict__ S, const float* __restrict__ AGG,
    const float* __restrict__ deg, const float* __restrict__ b, float* __restrict__ H)
{
    int idx = blockIdx.x * 256 + threadIdx.x;
    if (idx >= NN * NF4) return;
    int n = idx / NF4;
    int q = idx - n * NF4;
    float rd = 1.0f / fmaxf(deg[n], 1.0f);
    float4 s = ((const float4*)S)[idx];
    float4 a = ((const float4*)AGG)[idx];
    float4 bb = ((const float4*)b)[q];
    float4 r;
    r.x = s.x + a.x * rd + bb.x;
    r.y = s.y + a.y * rd + bb.y;
    r.z = s.z + a.z * rd + bb.z;
    r.w = s.w + a.w * rd + bb.w;
    if (RELU) {
        r.x = fmaxf(r.x, 0.f); r.y = fmaxf(r.y, 0.f);
        r.z = fmaxf(r.z, 0.f); r.w = fmaxf(r.w, 0.f);
    }
    ((float4*)H)[idx] = r;
}

// ---------------- edge MLP: score = W2 relu(W1 [h_u;h_v] + b1) + b2 --------
__global__ __launch_bounds__(256) void edge_mlp_kernel(
    const float* __restrict__ h2,
    const int* __restrict__ psrc, const int* __restrict__ pdst,
    const int* __restrict__ nsrc, const int* __restrict__ ndst,
    const float* __restrict__ Wp1, const float* __restrict__ bp1,
    const float* __restrict__ Wp2, const float* __restrict__ bp2,
    float* __restrict__ out)
{
    __shared__ float zsh[4][128];
    const int wave = threadIdx.x >> 6;
    const int lane = threadIdx.x & 63;
    const int e = blockIdx.x * 4 + wave;     // grid = 50000 exactly covers 200000
    int s, d;
    if (e < NP) { s = psrc[e]; d = pdst[e]; }
    else        { s = nsrc[e - NP]; d = ndst[e - NP]; }
    zsh[wave][lane]      = h2[(size_t)s * 64 + lane];
    zsh[wave][64 + lane] = h2[(size_t)d * 64 + lane];
    __syncthreads();
    float acc = bp1[lane];
    #pragma unroll 8
    for (int i = 0; i < 128; ++i)
        acc = fmaf(zsh[wave][i], Wp1[i * 64 + lane], acc);
    float hdn = fmaxf(acc, 0.0f);
    float p = hdn * Wp2[lane];
    #pragma unroll
    for (int off = 32; off > 0; off >>= 1)
        p += __shfl_down(p, off, 64);
    if (lane == 0) out[e] = p + bp2[0];
}

extern "C" void kernel_launch(void* const* d_in, const int* in_sizes, int n_in,
                              void* d_out, int out_size, void* d_ws, size_t ws_size,
                              hipStream_t stream) {
    (void)in_sizes; (void)n_in; (void)out_size; (void)ws_size;
    const float* x       = (const float*)d_in[0];
    const int*   esrc    = (const int*)d_in[1];
    const int*   edst    = (const int*)d_in[2];
    const int*   psrc    = (const int*)d_in[3];
    const int*   pdst    = (const int*)d_in[4];
    const int*   nsrc    = (const int*)d_in[5];
    const int*   ndst    = (const int*)d_in[6];
    const float* Wself1  = (const float*)d_in[7];
    const float* Wneigh1 = (const float*)d_in[8];
    const float* b1      = (const float*)d_in[9];
    const float* Wself2  = (const float*)d_in[10];
    const float* Wneigh2 = (const float*)d_in[11];
    const float* b2      = (const float*)d_in[12];
    const float* Wp1     = (const float*)d_in[13];
    const float* bp1     = (const float*)d_in[14];
    const float* Wp2     = (const float*)d_in[15];
    const float* bp2     = (const float*)d_in[16];
    float* out = (float*)d_out;

    float* ws   = (float*)d_ws;
    float* deg  = ws;                         // 50000 (padded to 50048)
    float* S1   = ws + 50048;                 // 50000*256
    float* N1   = S1 + (size_t)NN * DH;       // 50000*256
    float* AGG1 = N1 + (size_t)NN * DH;       // 50000*256
    // layer-2 buffers reuse AGG1's region after combine1 consumes it
    float* S2   = AGG1;                       // 50000*64
    float* N2   = AGG1 + (size_t)NN * DO;     // 50000*64
    float* AGG2 = AGG1 + 2 * (size_t)NN * DO; // 50000*64

    hipMemsetAsync(deg, 0, NN * sizeof(float), stream);
    hipMemsetAsync(AGG1, 0, (size_t)NN * DH * sizeof(float), stream);

    deg_kernel<<<(NE + 255) / 256, 256, 0, stream>>>(edst, deg);

    dim3 g1(DH / 128, (NN + 127) / 128);      // (2, 391)
    sgemm128<<<g1, 256, 0, stream>>>(x, Wself1,  S1, NN, DH, DIN);
    sgemm128<<<g1, 256, 0, stream>>>(x, Wneigh1, N1, NN, DH, DIN);

    scatter_kernel<64><<<(NE * 64) / 256, 256, 0, stream>>>(N1, esrc, edst, AGG1);
    combine_kernel<64, true><<<(NN * 64) / 256, 256, 0, stream>>>(S1, AGG1, deg, b1, S1); // h1 in-place

    hipMemsetAsync(AGG2, 0, (size_t)NN * DO * sizeof(float), stream);

    dim3 g2(1, (NN + 63) / 64);               // (1, 782)
    sgemm64<<<g2, 256, 0, stream>>>(S1, Wself2,  S2, NN, DO, DH);
    sgemm64<<<g2, 256, 0, stream>>>(S1, Wneigh2, N2, NN, DO, DH);

    scatter_kernel<16><<<(NE * 16) / 256, 256, 0, stream>>>(N2, esrc, edst, AGG2);
    combine_kernel<16, false><<<(NN * 16) / 256, 256, 0, stream>>>(S2, AGG2, deg, b2, S2); // h2 in-place

    edge_mlp_kernel<<<(2 * NP) / 4, 256, 0, stream>>>(S2, psrc, pdst, nsrc, ndst,
                                                      Wp1, bp1, Wp2, bp2, out);
}

// Round 2
// 733.795 us; speedup vs baseline: 1.8751x; 1.8751x over previous
//
#include <hip/hip_runtime.h>

#define NN 50000      // nodes
#define NE 160000     // graph edges
#define NP 100000     // pos (=neg) edges
#define DIN 512
#define DH  256
#define DO  64
#define NBLK_SCAN 196 // ceil(50000/256)

// ---------------- degree count (int) ----------------
__global__ __launch_bounds__(256) void deg_count(const int* __restrict__ dst, int* __restrict__ deg) {
    int e = blockIdx.x * 256 + threadIdx.x;
    if (e < NE) atomicAdd(&deg[dst[e]], 1);
}

// ---------------- exclusive scan (3-phase) ----------------
__global__ __launch_bounds__(256) void scan_part(const int* __restrict__ deg, int* __restrict__ excl,
                                                 int* __restrict__ bsums) {
    __shared__ int sh[256];
    int i = blockIdx.x * 256 + threadIdx.x;
    int v = (i < NN) ? deg[i] : 0;
    sh[threadIdx.x] = v;
    __syncthreads();
    #pragma unroll
    for (int off = 1; off < 256; off <<= 1) {
        int t = (threadIdx.x >= off) ? sh[threadIdx.x - off] : 0;
        __syncthreads();
        sh[threadIdx.x] += t;
        __syncthreads();
    }
    if (i < NN) excl[i] = sh[threadIdx.x] - v;
    if (threadIdx.x == 255) bsums[blockIdx.x] = sh[255];
}

__global__ __launch_bounds__(256) void scan_sums(int* __restrict__ bsums, int* __restrict__ boff) {
    __shared__ int sh[256];
    int v = (threadIdx.x < NBLK_SCAN) ? bsums[threadIdx.x] : 0;
    sh[threadIdx.x] = v;
    __syncthreads();
    #pragma unroll
    for (int off = 1; off < 256; off <<= 1) {
        int t = (threadIdx.x >= off) ? sh[threadIdx.x - off] : 0;
        __syncthreads();
        sh[threadIdx.x] += t;
        __syncthreads();
    }
    boff[threadIdx.x] = sh[threadIdx.x] - v;
}

__global__ __launch_bounds__(256) void scan_add(int* __restrict__ off, const int* __restrict__ boff,
                                                int* __restrict__ cursor) {
    int i = blockIdx.x * 256 + threadIdx.x;
    if (i < NN) {
        int o = off[i] + boff[blockIdx.x];
        off[i] = o;
        cursor[i] = o;
    }
    if (i == 0) off[NN] = NE;
}

// ---------------- CSR bucket fill ----------------
__global__ __launch_bounds__(256) void fill_csr(const int* __restrict__ src, const int* __restrict__ dst,
                                                int* __restrict__ cursor, int* __restrict__ eidx) {
    int e = blockIdx.x * 256 + threadIdx.x;
    if (e < NE) {
        int p = atomicAdd(&cursor[dst[e]], 1);
        eidx[p] = src[e];
    }
}

// ---------------- fp32 SGEMM, BM=BN=128, BK=16, 8x8 per thread ----------------
__global__ __launch_bounds__(256) void sgemm128(
    const float* __restrict__ A, const float* __restrict__ B, float* __restrict__ C,
    int M, int N, int K)
{
    __shared__ float As[16][128];
    __shared__ float Bs[16][128];
    const int tid = threadIdx.x;
    const int tx = tid & 15, ty = tid >> 4;
    const int row0 = blockIdx.y * 128, col0 = blockIdx.x * 128;

    float acc[8][8];
    #pragma unroll
    for (int i = 0; i < 8; ++i)
        #pragma unroll
        for (int j = 0; j < 8; ++j) acc[i][j] = 0.0f;

    for (int k0 = 0; k0 < K; k0 += 16) {
        __syncthreads();
        #pragma unroll
        for (int u = 0; u < 2; ++u) {
            int f4 = tid * 2 + u;            // 0..511
            int arow = f4 >> 2, ac4 = f4 & 3;
            float4 v = make_float4(0.f, 0.f, 0.f, 0.f);
            int r = row0 + arow;
            if (r < M) v = *(const float4*)&A[(size_t)r * K + k0 + ac4 * 4];
            As[ac4 * 4 + 0][arow] = v.x;
            As[ac4 * 4 + 1][arow] = v.y;
            As[ac4 * 4 + 2][arow] = v.z;
            As[ac4 * 4 + 3][arow] = v.w;
            int brow = f4 >> 5, bc4 = f4 & 31;
            float4 w = *(const float4*)&B[(size_t)(k0 + brow) * N + col0 + bc4 * 4];
            *(float4*)&Bs[brow][bc4 * 4] = w;
        }
        __syncthreads();
        #pragma unroll
        for (int kk = 0; kk < 16; ++kk) {
            float a[8], b[8];
            *(float4*)&a[0] = *(const float4*)&As[kk][ty * 8];
            *(float4*)&a[4] = *(const float4*)&As[kk][ty * 8 + 4];
            *(float4*)&b[0] = *(const float4*)&Bs[kk][tx * 8];
            *(float4*)&b[4] = *(const float4*)&Bs[kk][tx * 8 + 4];
            #pragma unroll
            for (int i = 0; i < 8; ++i)
                #pragma unroll
                for (int j = 0; j < 8; ++j)
                    acc[i][j] = fmaf(a[i], b[j], acc[i][j]);
        }
    }
    #pragma unroll
    for (int i = 0; i < 8; ++i) {
        int r = row0 + ty * 8 + i;
        if (r < M) {
            *(float4*)&C[(size_t)r * N + col0 + tx * 8]     = make_float4(acc[i][0], acc[i][1], acc[i][2], acc[i][3]);
            *(float4*)&C[(size_t)r * N + col0 + tx * 8 + 4] = make_float4(acc[i][4], acc[i][5], acc[i][6], acc[i][7]);
        }
    }
}

// ---------------- fp32 SGEMM, BM=BN=64, BK=16, 4x4 per thread (layer 2, N=64) ----
__global__ __launch_bounds__(256) void sgemm64(
    const float* __restrict__ A, const float* __restrict__ B, float* __restrict__ C,
    int M, int N, int K)
{
    __shared__ float As[16][64];
    __shared__ float Bs[16][64];
    const int tid = threadIdx.x;
    const int tx = tid & 15, ty = tid >> 4;
    const int row0 = blockIdx.y * 64, col0 = blockIdx.x * 64;

    float acc[4][4];
    #pragma unroll
    for (int i = 0; i < 4; ++i)
        #pragma unroll
        for (int j = 0; j < 4; ++j) acc[i][j] = 0.0f;

    for (int k0 = 0; k0 < K; k0 += 16) {
        __syncthreads();
        {
            int arow = tid >> 2, ac4 = tid & 3;
            float4 v = make_float4(0.f, 0.f, 0.f, 0.f);
            int r = row0 + arow;
            if (r < M) v = *(const float4*)&A[(size_t)r * K + k0 + ac4 * 4];
            As[ac4 * 4 + 0][arow] = v.x;
            As[ac4 * 4 + 1][arow] = v.y;
            As[ac4 * 4 + 2][arow] = v.z;
            As[ac4 * 4 + 3][arow] = v.w;
            int brow = tid >> 4, bc4 = tid & 15;
            float4 w = *(const float4*)&B[(size_t)(k0 + brow) * N + col0 + bc4 * 4];
            *(float4*)&Bs[brow][bc4 * 4] = w;
        }
        __syncthreads();
        #pragma unroll
        for (int kk = 0; kk < 16; ++kk) {
            float a[4], b[4];
            *(float4*)&a[0] = *(const float4*)&As[kk][ty * 4];
            *(float4*)&b[0] = *(const float4*)&Bs[kk][tx * 4];
            #pragma unroll
            for (int i = 0; i < 4; ++i)
                #pragma unroll
                for (int j = 0; j < 4; ++j)
                    acc[i][j] = fmaf(a[i], b[j], acc[i][j]);
        }
    }
    #pragma unroll
    for (int i = 0; i < 4; ++i) {
        int r = row0 + ty * 4 + i;
        if (r < M)
            *(float4*)&C[(size_t)r * N + col0 + tx * 4] = make_float4(acc[i][0], acc[i][1], acc[i][2], acc[i][3]);
    }
}

// ---------------- gather-aggregate + combine, 256 feats (layer 1, relu) ------
// one wave per node; lane holds float4 (4 feats)
__global__ __launch_bounds__(256) void agg_combine256(
    const float* __restrict__ S, const float* __restrict__ V,
    const int* __restrict__ off, const int* __restrict__ eidx,
    const float* __restrict__ b, float* __restrict__ H)
{
    const int wave = threadIdx.x >> 6, lane = threadIdx.x & 63;
    const int n = blockIdx.x * 4 + wave;
    if (n >= NN) return;
    const int e0 = off[n], e1 = off[n + 1];
    float4 acc = make_float4(0.f, 0.f, 0.f, 0.f);
    for (int e = e0; e < e1; ++e) {
        int s = eidx[e];
        float4 v = ((const float4*)V)[(size_t)s * 64 + lane];
        acc.x += v.x; acc.y += v.y; acc.z += v.z; acc.w += v.w;
    }
    const float rd = (e1 > e0) ? 1.0f / (float)(e1 - e0) : 1.0f;
    float4 s4 = ((const float4*)S)[(size_t)n * 64 + lane];
    float4 bb = ((const float4*)b)[lane];
    float4 r;
    r.x = fmaxf(s4.x + acc.x * rd + bb.x, 0.f);
    r.y = fmaxf(s4.y + acc.y * rd + bb.y, 0.f);
    r.z = fmaxf(s4.z + acc.z * rd + bb.z, 0.f);
    r.w = fmaxf(s4.w + acc.w * rd + bb.w, 0.f);
    ((float4*)H)[(size_t)n * 64 + lane] = r;
}

// ---------------- gather-aggregate + combine, 64 feats (layer 2, no relu) ----
__global__ __launch_bounds__(256) void agg_combine64(
    const float* __restrict__ S, const float* __restrict__ V,
    const int* __restrict__ off, const int* __restrict__ eidx,
    const float* __restrict__ b, float* __restrict__ H)
{
    const int wave = threadIdx.x >> 6, lane = threadIdx.x & 63;
    const int n = blockIdx.x * 4 + wave;
    if (n >= NN) return;
    const int e0 = off[n], e1 = off[n + 1];
    float acc = 0.f;
    for (int e = e0; e < e1; ++e) {
        int s = eidx[e];
        acc += V[(size_t)s * 64 + lane];
    }
    const float rd = (e1 > e0) ? 1.0f / (float)(e1 - e0) : 1.0f;
    H[(size_t)n * 64 + lane] = S[(size_t)n * 64 + lane] + acc * rd + b[lane];
}

// ---------------- edge MLP: score = W2 relu(W1 [h_u;h_v] + b1) + b2 --------
__global__ __launch_bounds__(256) void edge_mlp_kernel(
    const float* __restrict__ h2,
    const int* __restrict__ psrc, const int* __restrict__ pdst,
    const int* __restrict__ nsrc, const int* __restrict__ ndst,
    const float* __restrict__ Wp1, const float* __restrict__ bp1,
    const float* __restrict__ Wp2, const float* __restrict__ bp2,
    float* __restrict__ out)
{
    __shared__ float zsh[4][128];
    const int wave = threadIdx.x >> 6;
    const int lane = threadIdx.x & 63;
    const int e = blockIdx.x * 4 + wave;     // grid = 50000 exactly covers 200000
    int s, d;
    if (e < NP) { s = psrc[e]; d = pdst[e]; }
    else        { s = nsrc[e - NP]; d = ndst[e - NP]; }
    zsh[wave][lane]      = h2[(size_t)s * 64 + lane];
    zsh[wave][64 + lane] = h2[(size_t)d * 64 + lane];
    __syncthreads();
    float acc = bp1[lane];
    #pragma unroll 8
    for (int i = 0; i < 128; ++i)
        acc = fmaf(zsh[wave][i], Wp1[i * 64 + lane], acc);
    float hdn = fmaxf(acc, 0.0f);
    float p = hdn * Wp2[lane];
    #pragma unroll
    for (int off = 32; off > 0; off >>= 1)
        p += __shfl_down(p, off, 64);
    if (lane == 0) out[e] = p + bp2[0];
}

extern "C" void kernel_launch(void* const* d_in, const int* in_sizes, int n_in,
                              void* d_out, int out_size, void* d_ws, size_t ws_size,
                              hipStream_t stream) {
    (void)in_sizes; (void)n_in; (void)out_size; (void)ws_size;
    const float* x       = (const float*)d_in[0];
    const int*   esrc    = (const int*)d_in[1];
    const int*   edst    = (const int*)d_in[2];
    const int*   psrc    = (const int*)d_in[3];
    const int*   pdst    = (const int*)d_in[4];
    const int*   nsrc    = (const int*)d_in[5];
    const int*   ndst    = (const int*)d_in[6];
    const float* Wself1  = (const float*)d_in[7];
    const float* Wneigh1 = (const float*)d_in[8];
    const float* b1      = (const float*)d_in[9];
    const float* Wself2  = (const float*)d_in[10];
    const float* Wneigh2 = (const float*)d_in[11];
    const float* b2      = (const float*)d_in[12];
    const float* Wp1     = (const float*)d_in[13];
    const float* bp1     = (const float*)d_in[14];
    const float* Wp2     = (const float*)d_in[15];
    const float* bp2     = (const float*)d_in[16];
    float* out = (float*)d_out;

    // -------- workspace carve-up (16B-aligned chunks) --------
    char* w = (char*)d_ws;
    int* deg_i  = (int*)w; w += 50048 * 4;
    int* off    = (int*)w; w += 50052 * 4;   // off[NN] inclusive end
    int* cursor = (int*)w; w += 50048 * 4;
    int* bsums  = (int*)w; w += 256 * 4;
    int* boff   = (int*)w; w += 256 * 4;
    int* eidx   = (int*)w; w += 160000 * 4;
    float* S1 = (float*)w; w += (size_t)NN * DH * 4;
    float* N1 = (float*)w; w += (size_t)NN * DH * 4;
    float* S2 = (float*)w; w += (size_t)NN * DO * 4;
    float* N2 = (float*)w; w += (size_t)NN * DO * 4;

    // -------- CSR build --------
    hipMemsetAsync(deg_i, 0, 50048 * 4, stream);
    deg_count<<<(NE + 255) / 256, 256, 0, stream>>>(edst, deg_i);
    scan_part<<<NBLK_SCAN, 256, 0, stream>>>(deg_i, off, bsums);
    scan_sums<<<1, 256, 0, stream>>>(bsums, boff);
    scan_add<<<NBLK_SCAN, 256, 0, stream>>>(off, boff, cursor);
    fill_csr<<<(NE + 255) / 256, 256, 0, stream>>>(esrc, edst, cursor, eidx);

    // -------- layer 1: GEMMs then gather-aggregate+combine --------
    dim3 g1(DH / 128, (NN + 127) / 128);      // (2, 391)
    sgemm128<<<g1, 256, 0, stream>>>(x, Wself1,  S1, NN, DH, DIN);
    sgemm128<<<g1, 256, 0, stream>>>(x, Wneigh1, N1, NN, DH, DIN);
    agg_combine256<<<(NN + 3) / 4, 256, 0, stream>>>(S1, N1, off, eidx, b1, S1); // h1 -> S1

    // -------- layer 2 --------
    dim3 g2(1, (NN + 63) / 64);               // (1, 782)
    sgemm64<<<g2, 256, 0, stream>>>(S1, Wself2,  S2, NN, DO, DH);
    sgemm64<<<g2, 256, 0, stream>>>(S1, Wneigh2, N2, NN, DO, DH);
    agg_combine64<<<(NN + 3) / 4, 256, 0, stream>>>(S2, N2, off, eidx, b2, S2);  // h2 -> S2

    // -------- edge scorer --------
    edge_mlp_kernel<<<(2 * NP) / 4, 256, 0, stream>>>(S2, psrc, pdst, nsrc, ndst,
                                                      Wp1, bp1, Wp2, bp2, out);
}

// Round 3
// 377.131 us; speedup vs baseline: 3.6485x; 1.9457x over previous
//
#include <hip/hip_runtime.h>

#define NN 50000      // nodes
#define NE 160000     // graph edges
#define NP 100000     // pos (=neg) edges
#define DIN 512
#define DH  256
#define DO  64
#define NBLK_SCAN 196 // ceil(50000/256)

typedef short bf16x8 __attribute__((ext_vector_type(8)));
typedef float f32x4  __attribute__((ext_vector_type(4)));

__device__ __forceinline__ float bf2f(unsigned short u) {
    return __uint_as_float(((unsigned int)u) << 16);
}
__device__ __forceinline__ unsigned short f2bf(float f) {
    unsigned int x = __float_as_uint(f);
    return (unsigned short)((x + 0x7fffu + ((x >> 16) & 1u)) >> 16);
}

__device__ __forceinline__ void gload_lds16(const void* g, void* l) {
    __builtin_amdgcn_global_load_lds(
        (const __attribute__((address_space(1))) void*)g,
        (__attribute__((address_space(3))) void*)l, 16, 0, 0);
}

// ---------------- CSR build ----------------
__global__ __launch_bounds__(256) void deg_count(const int* __restrict__ dst, int* __restrict__ deg) {
    int e = blockIdx.x * 256 + threadIdx.x;
    if (e < NE) atomicAdd(&deg[dst[e]], 1);
}

__global__ __launch_bounds__(256) void scan_part(const int* __restrict__ deg, int* __restrict__ excl,
                                                 int* __restrict__ bsums) {
    __shared__ int sh[256];
    int i = blockIdx.x * 256 + threadIdx.x;
    int v = (i < NN) ? deg[i] : 0;
    sh[threadIdx.x] = v;
    __syncthreads();
    #pragma unroll
    for (int off = 1; off < 256; off <<= 1) {
        int t = (threadIdx.x >= off) ? sh[threadIdx.x - off] : 0;
        __syncthreads();
        sh[threadIdx.x] += t;
        __syncthreads();
    }
    if (i < NN) excl[i] = sh[threadIdx.x] - v;
    if (threadIdx.x == 255) bsums[blockIdx.x] = sh[255];
}

__global__ __launch_bounds__(256) void scan_sums(int* __restrict__ bsums, int* __restrict__ boff) {
    __shared__ int sh[256];
    int v = (threadIdx.x < NBLK_SCAN) ? bsums[threadIdx.x] : 0;
    sh[threadIdx.x] = v;
    __syncthreads();
    #pragma unroll
    for (int off = 1; off < 256; off <<= 1) {
        int t = (threadIdx.x >= off) ? sh[threadIdx.x - off] : 0;
        __syncthreads();
        sh[threadIdx.x] += t;
        __syncthreads();
    }
    boff[threadIdx.x] = sh[threadIdx.x] - v;
}

__global__ __launch_bounds__(256) void scan_add(int* __restrict__ off, const int* __restrict__ boff,
                                                int* __restrict__ cursor) {
    int i = blockIdx.x * 256 + threadIdx.x;
    if (i < NN) {
        int o = off[i] + boff[blockIdx.x];
        off[i] = o;
        cursor[i] = o;
    }
    if (i == 0) off[NN] = NE;
}

__global__ __launch_bounds__(256) void fill_csr(const int* __restrict__ src, const int* __restrict__ dst,
                                                int* __restrict__ cursor, int* __restrict__ eidx) {
    int e = blockIdx.x * 256 + threadIdx.x;
    if (e < NE) {
        int p = atomicAdd(&cursor[dst[e]], 1);
        eidx[p] = src[e];
    }
}

// ---------------- prep: fp32 -> bf16 conversions ----------------
__global__ __launch_bounds__(256) void cvt_x_kernel(const float* __restrict__ x, unsigned short* __restrict__ xb) {
    int i = blockIdx.x * 256 + threadIdx.x;   // one float4 per thread
    if (i >= NN * DIN / 4) return;
    float4 v = ((const float4*)x)[i];
    ushort4 o;
    o.x = f2bf(v.x); o.y = f2bf(v.y); o.z = f2bf(v.z); o.w = f2bf(v.w);
    ((ushort4*)xb)[i] = o;
}

// Bt[n][k] = W(k, n) for concatenated [W_self | W_neigh], bf16 out
__global__ __launch_bounds__(256) void prep_w(const float* __restrict__ Wself, const float* __restrict__ Wneigh,
                                              unsigned short* __restrict__ Bt, int K, int Nhalf) {
    int idx = blockIdx.x * 256 + threadIdx.x;
    int N = 2 * Nhalf;
    if (idx >= N * K) return;
    int n = idx / K, k = idx - n * K;
    float v = (n < Nhalf) ? Wself[(size_t)k * Nhalf + n] : Wneigh[(size_t)k * Nhalf + (n - Nhalf)];
    Bt[idx] = f2bf(v);
}

// ---------------- bf16 MFMA GEMM: C[M,N] = A[M,K] @ Bt[N,K]^T ----------------
// BM=BN=128, BK=64, 4 waves (2x2), each wave 64x64 out (4x4 frags of 16x16x32)
template<bool OUT_BF16>
__global__ __launch_bounds__(256) void gemm_bf16(
    const unsigned short* __restrict__ A, const unsigned short* __restrict__ Bt,
    void* __restrict__ Cout, int M, int N, int K)
{
    __shared__ unsigned short As[128 * 64];   // [row][k] with chunk-XOR swizzle
    __shared__ unsigned short Bs[128 * 64];   // [col][k] with chunk-XOR swizzle
    const int tid = threadIdx.x;
    const int w = tid >> 6, l = tid & 63;
    const int wr = (w >> 1) * 64, wc = (w & 1) * 64;
    const int row0 = blockIdx.y * 128, col0 = blockIdx.x * 128;

    f32x4 acc[4][4];
    #pragma unroll
    for (int i = 0; i < 4; ++i)
        #pragma unroll
        for (int j = 0; j < 4; ++j)
            #pragma unroll
            for (int r = 0; r < 4; ++r) acc[i][j][r] = 0.0f;

    const int wave_lds_chunk = (tid & 192) * 8;  // w*64 chunks -> *8 ushorts... (chunk=8 ushort)

    for (int k0 = 0; k0 < K; k0 += 64) {
        __syncthreads();
        // stage A tile: 1024 chunks of 16B, source pre-swizzled (involution j^row&7)
        #pragma unroll
        for (int u = 0; u < 4; ++u) {
            int c = u * 256 + tid;
            int row = c >> 3, j = c & 7;
            int js = j ^ (row & 7);
            int grow = row0 + row; if (grow >= M) grow = M - 1;
            gload_lds16(A + (size_t)grow * K + k0 + js * 8,
                        (void*)(As + (u * 256) * 8 + wave_lds_chunk));
        }
        #pragma unroll
        for (int u = 0; u < 4; ++u) {
            int c = u * 256 + tid;
            int cn = c >> 3, j = c & 7;
            int js = j ^ (cn & 7);
            gload_lds16(Bt + (size_t)(col0 + cn) * K + k0 + js * 8,
                        (void*)(Bs + (u * 256) * 8 + wave_lds_chunk));
        }
        __syncthreads();   // compiler emits vmcnt(0) drain here

        #pragma unroll
        for (int kk = 0; kk < 2; ++kk) {
            bf16x8 af[4], bf[4];
            #pragma unroll
            for (int i = 0; i < 4; ++i) {
                int row = wr + i * 16 + (l & 15);
                int ch = (kk * 4 + (l >> 4)) ^ (row & 7);
                af[i] = *(const bf16x8*)&As[row * 64 + ch * 8];
            }
            #pragma unroll
            for (int j = 0; j < 4; ++j) {
                int cc = wc + j * 16 + (l & 15);
                int ch = (kk * 4 + (l >> 4)) ^ (cc & 7);
                bf[j] = *(const bf16x8*)&Bs[cc * 64 + ch * 8];
            }
            #pragma unroll
            for (int i = 0; i < 4; ++i)
                #pragma unroll
                for (int j = 0; j < 4; ++j)
                    acc[i][j] = __builtin_amdgcn_mfma_f32_16x16x32_bf16(af[i], bf[j], acc[i][j], 0, 0, 0);
        }
    }

    // epilogue: C/D layout col=lane&15, row=(lane>>4)*4+reg
    #pragma unroll
    for (int i = 0; i < 4; ++i) {
        #pragma unroll
        for (int j = 0; j < 4; ++j) {
            int r0 = row0 + wr + i * 16 + ((l >> 4) << 2);
            int c  = col0 + wc + j * 16 + (l & 15);
            #pragma unroll
            for (int r = 0; r < 4; ++r) {
                if (r0 + r < M) {
                    if (OUT_BF16)
                        ((unsigned short*)Cout)[(size_t)(r0 + r) * N + c] = f2bf(acc[i][j][r]);
                    else
                        ((float*)Cout)[(size_t)(r0 + r) * N + c] = acc[i][j][r];
                }
            }
        }
    }
}

// ---------------- gather-aggregate + combine, layer 1 (bf16 in/out, relu) ----
// C1 row: cols [0,256) = self part, [256,512) = neigh part. One wave per node.
__global__ __launch_bounds__(256) void agg_combine256(
    const unsigned short* __restrict__ C1, const int* __restrict__ off, const int* __restrict__ eidx,
    const float* __restrict__ b, unsigned short* __restrict__ h1b)
{
    const int wave = threadIdx.x >> 6, lane = threadIdx.x & 63;
    const int n = blockIdx.x * 4 + wave;
    if (n >= NN) return;
    const int e0 = off[n], e1 = off[n + 1];
    float acc0 = 0.f, acc1 = 0.f, acc2 = 0.f, acc3 = 0.f;
    for (int e = e0; e < e1; ++e) {
        int s = eidx[e];
        ushort4 v = *(const ushort4*)&C1[(size_t)s * 512 + 256 + lane * 4];
        acc0 += bf2f(v.x); acc1 += bf2f(v.y); acc2 += bf2f(v.z); acc3 += bf2f(v.w);
    }
    const float rd = (e1 > e0) ? 1.0f / (float)(e1 - e0) : 1.0f;
    ushort4 sv = *(const ushort4*)&C1[(size_t)n * 512 + lane * 4];
    float4 bb = ((const float4*)b)[lane];
    ushort4 o;
    o.x = f2bf(fmaxf(bf2f(sv.x) + acc0 * rd + bb.x, 0.f));
    o.y = f2bf(fmaxf(bf2f(sv.y) + acc1 * rd + bb.y, 0.f));
    o.z = f2bf(fmaxf(bf2f(sv.z) + acc2 * rd + bb.z, 0.f));
    o.w = f2bf(fmaxf(bf2f(sv.w) + acc3 * rd + bb.w, 0.f));
    *(ushort4*)&h1b[(size_t)n * 256 + lane * 4] = o;
}

// ---------------- gather-aggregate + combine, layer 2 (fp32, no relu) --------
// C2 row: cols [0,64) self, [64,128) neigh
__global__ __launch_bounds__(256) void agg_combine64(
    const float* __restrict__ C2, const int* __restrict__ off, const int* __restrict__ eidx,
    const float* __restrict__ b, float* __restrict__ h2)
{
    const int wave = threadIdx.x >> 6, lane = threadIdx.x & 63;
    const int n = blockIdx.x * 4 + wave;
    if (n >= NN) return;
    const int e0 = off[n], e1 = off[n + 1];
    float acc = 0.f;
    for (int e = e0; e < e1; ++e) {
        int s = eidx[e];
        acc += C2[(size_t)s * 128 + 64 + lane];
    }
    const float rd = (e1 > e0) ? 1.0f / (float)(e1 - e0) : 1.0f;
    h2[(size_t)n * 64 + lane] = C2[(size_t)n * 128 + lane] + acc * rd + b[lane];
}

// ---------------- edge MLP: score = W2 relu(W1 [h_u;h_v] + b1) + b2 --------
__global__ __launch_bounds__(256) void edge_mlp_kernel(
    const float* __restrict__ h2,
    const int* __restrict__ psrc, const int* __restrict__ pdst,
    const int* __restrict__ nsrc, const int* __restrict__ ndst,
    const float* __restrict__ Wp1, const float* __restrict__ bp1,
    const float* __restrict__ Wp2, const float* __restrict__ bp2,
    float* __restrict__ out)
{
    __shared__ float zsh[4][128];
    const int wave = threadIdx.x >> 6;
    const int lane = threadIdx.x & 63;
    const int e = blockIdx.x * 4 + wave;     // grid = 50000 exactly covers 200000
    int s, d;
    if (e < NP) { s = psrc[e]; d = pdst[e]; }
    else        { s = nsrc[e - NP]; d = ndst[e - NP]; }
    zsh[wave][lane]      = h2[(size_t)s * 64 + lane];
    zsh[wave][64 + lane] = h2[(size_t)d * 64 + lane];
    __syncthreads();
    float acc = bp1[lane];
    #pragma unroll 8
    for (int i = 0; i < 128; ++i)
        acc = fmaf(zsh[wave][i], Wp1[i * 64 + lane], acc);
    float hdn = fmaxf(acc, 0.0f);
    float p = hdn * Wp2[lane];
    #pragma unroll
    for (int off = 32; off > 0; off >>= 1)
        p += __shfl_down(p, off, 64);
    if (lane == 0) out[e] = p + bp2[0];
}

extern "C" void kernel_launch(void* const* d_in, const int* in_sizes, int n_in,
                              void* d_out, int out_size, void* d_ws, size_t ws_size,
                              hipStream_t stream) {
    (void)in_sizes; (void)n_in; (void)out_size; (void)ws_size;
    const float* x       = (const float*)d_in[0];
    const int*   esrc    = (const int*)d_in[1];
    const int*   edst    = (const int*)d_in[2];
    const int*   psrc    = (const int*)d_in[3];
    const int*   pdst    = (const int*)d_in[4];
    const int*   nsrc    = (const int*)d_in[5];
    const int*   ndst    = (const int*)d_in[6];
    const float* Wself1  = (const float*)d_in[7];
    const float* Wneigh1 = (const float*)d_in[8];
    const float* b1      = (const float*)d_in[9];
    const float* Wself2  = (const float*)d_in[10];
    const float* Wneigh2 = (const float*)d_in[11];
    const float* b2      = (const float*)d_in[12];
    const float* Wp1     = (const float*)d_in[13];
    const float* bp1     = (const float*)d_in[14];
    const float* Wp2     = (const float*)d_in[15];
    const float* bp2     = (const float*)d_in[16];
    float* out = (float*)d_out;

    // -------- workspace carve-up --------
    char* w = (char*)d_ws;
    int* deg_i  = (int*)w; w += 50048 * 4;
    int* off    = (int*)w; w += 50052 * 4;
    int* cursor = (int*)w; w += 50048 * 4;
    int* bsums  = (int*)w; w += 256 * 4;
    int* boff   = (int*)w; w += 256 * 4;
    int* eidx   = (int*)w; w += 160000 * 4;
    unsigned short* Bt1 = (unsigned short*)w; w += (size_t)512 * 512 * 2;
    unsigned short* Bt2 = (unsigned short*)w; w += (size_t)128 * 256 * 2;
    unsigned short* xb  = (unsigned short*)w; w += (size_t)NN * DIN * 2;  // 51.2 MB
    unsigned short* C1b = (unsigned short*)w; w += (size_t)NN * 512 * 2;  // 51.2 MB
    // aliases: xb dead after GEMM1 -> h1b, h2 live there; C1b dead after agg1 -> C2
    unsigned short* h1b = xb;                                  // 25.6 MB
    float* h2 = (float*)(xb + (size_t)NN * DH);                // 12.8 MB, within xb region
    float* C2 = (float*)C1b;                                   // 25.6 MB

    // -------- CSR build --------
    hipMemsetAsync(deg_i, 0, 50048 * 4, stream);
    deg_count<<<(NE + 255) / 256, 256, 0, stream>>>(edst, deg_i);
    scan_part<<<NBLK_SCAN, 256, 0, stream>>>(deg_i, off, bsums);
    scan_sums<<<1, 256, 0, stream>>>(bsums, boff);
    scan_add<<<NBLK_SCAN, 256, 0, stream>>>(off, boff, cursor);
    fill_csr<<<(NE + 255) / 256, 256, 0, stream>>>(esrc, edst, cursor, eidx);

    // -------- prep conversions --------
    cvt_x_kernel<<<(NN * DIN / 4 + 255) / 256, 256, 0, stream>>>(x, xb);
    prep_w<<<(512 * 512 + 255) / 256, 256, 0, stream>>>(Wself1, Wneigh1, Bt1, DIN, DH);
    prep_w<<<(128 * 256 + 255) / 256, 256, 0, stream>>>(Wself2, Wneigh2, Bt2, DH, DO);

    // -------- layer 1 --------
    dim3 g1(512 / 128, (NN + 127) / 128);     // (4, 391)
    gemm_bf16<true><<<g1, 256, 0, stream>>>(xb, Bt1, C1b, NN, 512, DIN);
    agg_combine256<<<(NN + 3) / 4, 256, 0, stream>>>(C1b, off, eidx, b1, h1b);

    // -------- layer 2 --------
    dim3 g2(1, (NN + 127) / 128);             // (1, 391)
    gemm_bf16<false><<<g2, 256, 0, stream>>>(h1b, Bt2, C2, NN, 128, DH);
    agg_combine64<<<(NN + 3) / 4, 256, 0, stream>>>(C2, off, eidx, b2, h2);

    // -------- edge scorer --------
    edge_mlp_kernel<<<(2 * NP) / 4, 256, 0, stream>>>(h2, psrc, pdst, nsrc, ndst,
                                                      Wp1, bp1, Wp2, bp2, out);
}

// Round 4
// 216.180 us; speedup vs baseline: 6.3649x; 1.7445x over previous
//
#include <hip/hip_runtime.h>

#define NN 50000      // nodes
#define NE 160000     // graph edges
#define NP 100000     // pos (=neg) edges
#define DIN 512
#define DH  256
#define DO  64
#define NBLK_SCAN 196 // ceil(50000/256)

typedef short bf16x8 __attribute__((ext_vector_type(8)));
typedef float f32x4  __attribute__((ext_vector_type(4)));

__device__ __forceinline__ float bf2f(unsigned short u) {
    return __uint_as_float(((unsigned int)u) << 16);
}
__device__ __forceinline__ unsigned short f2bf(float f) {
    unsigned int x = __float_as_uint(f);
    return (unsigned short)((x + 0x7fffu + ((x >> 16) & 1u)) >> 16);
}

__device__ __forceinline__ void gload_lds16(const void* g, void* l) {
    __builtin_amdgcn_global_load_lds(
        (const __attribute__((address_space(1))) void*)g,
        (__attribute__((address_space(3))) void*)l, 16, 0, 0);
}

// ---------------- CSR build ----------------
__global__ __launch_bounds__(256) void deg_count(const int* __restrict__ dst, int* __restrict__ deg) {
    int e = blockIdx.x * 256 + threadIdx.x;
    if (e < NE) atomicAdd(&deg[dst[e]], 1);
}

__global__ __launch_bounds__(256) void scan_part(const int* __restrict__ deg, int* __restrict__ excl,
                                                 int* __restrict__ bsums) {
    __shared__ int sh[256];
    int i = blockIdx.x * 256 + threadIdx.x;
    int v = (i < NN) ? deg[i] : 0;
    sh[threadIdx.x] = v;
    __syncthreads();
    #pragma unroll
    for (int off = 1; off < 256; off <<= 1) {
        int t = (threadIdx.x >= off) ? sh[threadIdx.x - off] : 0;
        __syncthreads();
        sh[threadIdx.x] += t;
        __syncthreads();
    }
    if (i < NN) excl[i] = sh[threadIdx.x] - v;
    if (threadIdx.x == 255) bsums[blockIdx.x] = sh[255];
}

__global__ __launch_bounds__(256) void scan_sums(int* __restrict__ bsums, int* __restrict__ boff) {
    __shared__ int sh[256];
    int v = (threadIdx.x < NBLK_SCAN) ? bsums[threadIdx.x] : 0;
    sh[threadIdx.x] = v;
    __syncthreads();
    #pragma unroll
    for (int off = 1; off < 256; off <<= 1) {
        int t = (threadIdx.x >= off) ? sh[threadIdx.x - off] : 0;
        __syncthreads();
        sh[threadIdx.x] += t;
        __syncthreads();
    }
    boff[threadIdx.x] = sh[threadIdx.x] - v;
}

__global__ __launch_bounds__(256) void scan_add(int* __restrict__ off, const int* __restrict__ boff,
                                                int* __restrict__ cursor) {
    int i = blockIdx.x * 256 + threadIdx.x;
    if (i < NN) {
        int o = off[i] + boff[blockIdx.x];
        off[i] = o;
        cursor[i] = o;
    }
    if (i == 0) off[NN] = NE;
}

__global__ __launch_bounds__(256) void fill_csr(const int* __restrict__ src, const int* __restrict__ dst,
                                                int* __restrict__ cursor, int* __restrict__ eidx) {
    int e = blockIdx.x * 256 + threadIdx.x;
    if (e < NE) {
        int p = atomicAdd(&cursor[dst[e]], 1);
        eidx[p] = src[e];
    }
}

// ---------------- prep: fp32 -> bf16 conversions ----------------
__global__ __launch_bounds__(256) void cvt_x_kernel(const float* __restrict__ x, unsigned short* __restrict__ xb) {
    int i = blockIdx.x * 256 + threadIdx.x;   // one float4 per thread
    if (i >= NN * DIN / 4) return;
    float4 v = ((const float4*)x)[i];
    ushort4 o;
    o.x = f2bf(v.x); o.y = f2bf(v.y); o.z = f2bf(v.z); o.w = f2bf(v.w);
    ((ushort4*)xb)[i] = o;
}

// Bt[n][k] = W(k, n) for concatenated [W_self | W_neigh], bf16 out
__global__ __launch_bounds__(256) void prep_w(const float* __restrict__ Wself, const float* __restrict__ Wneigh,
                                              unsigned short* __restrict__ Bt, int K, int Nhalf) {
    int idx = blockIdx.x * 256 + threadIdx.x;
    int N = 2 * Nhalf;
    if (idx >= N * K) return;
    int n = idx / K, k = idx - n * K;
    float v = (n < Nhalf) ? Wself[(size_t)k * Nhalf + n] : Wneigh[(size_t)k * Nhalf + (n - Nhalf)];
    Bt[idx] = f2bf(v);
}

// Wp1b[n][k] = Wp1[k][n], bf16 (n<64, k<128)
__global__ __launch_bounds__(256) void prep_wp1(const float* __restrict__ Wp1, unsigned short* __restrict__ Wp1b) {
    int idx = blockIdx.x * 256 + threadIdx.x;
    if (idx >= 64 * 128) return;
    int n = idx >> 7, k = idx & 127;
    Wp1b[idx] = f2bf(Wp1[(size_t)k * 64 + n]);
}

// ---------------- bf16 MFMA GEMM: C[M,N] = A[M,K] @ Bt[N,K]^T ----------------
// BM=BN=128, BK=64, 4 waves (2x2), each wave 64x64 out (4x4 frags of 16x16x32)
template<bool OUT_BF16>
__global__ __launch_bounds__(256) void gemm_bf16(
    const unsigned short* __restrict__ A, const unsigned short* __restrict__ Bt,
    void* __restrict__ Cout, int M, int N, int K)
{
    __shared__ unsigned short As[128 * 64];   // [row][k] with chunk-XOR swizzle
    __shared__ unsigned short Bs[128 * 64];   // [col][k] with chunk-XOR swizzle
    const int tid = threadIdx.x;
    const int w = tid >> 6, l = tid & 63;
    const int wr = (w >> 1) * 64, wc = (w & 1) * 64;
    const int row0 = blockIdx.y * 128, col0 = blockIdx.x * 128;

    f32x4 acc[4][4];
    #pragma unroll
    for (int i = 0; i < 4; ++i)
        #pragma unroll
        for (int j = 0; j < 4; ++j)
            #pragma unroll
            for (int r = 0; r < 4; ++r) acc[i][j][r] = 0.0f;

    const int wave_lds_chunk = (tid & 192) * 8;

    for (int k0 = 0; k0 < K; k0 += 64) {
        __syncthreads();
        #pragma unroll
        for (int u = 0; u < 4; ++u) {
            int c = u * 256 + tid;
            int row = c >> 3, j = c & 7;
            int js = j ^ (row & 7);
            int grow = row0 + row; if (grow >= M) grow = M - 1;
            gload_lds16(A + (size_t)grow * K + k0 + js * 8,
                        (void*)(As + (u * 256) * 8 + wave_lds_chunk));
        }
        #pragma unroll
        for (int u = 0; u < 4; ++u) {
            int c = u * 256 + tid;
            int cn = c >> 3, j = c & 7;
            int js = j ^ (cn & 7);
            gload_lds16(Bt + (size_t)(col0 + cn) * K + k0 + js * 8,
                        (void*)(Bs + (u * 256) * 8 + wave_lds_chunk));
        }
        __syncthreads();

        #pragma unroll
        for (int kk = 0; kk < 2; ++kk) {
            bf16x8 af[4], bfv[4];
            #pragma unroll
            for (int i = 0; i < 4; ++i) {
                int row = wr + i * 16 + (l & 15);
                int ch = (kk * 4 + (l >> 4)) ^ (row & 7);
                af[i] = *(const bf16x8*)&As[row * 64 + ch * 8];
            }
            #pragma unroll
            for (int j = 0; j < 4; ++j) {
                int cc = wc + j * 16 + (l & 15);
                int ch = (kk * 4 + (l >> 4)) ^ (cc & 7);
                bfv[j] = *(const bf16x8*)&Bs[cc * 64 + ch * 8];
            }
            #pragma unroll
            for (int i = 0; i < 4; ++i)
                #pragma unroll
                for (int j = 0; j < 4; ++j)
                    acc[i][j] = __builtin_amdgcn_mfma_f32_16x16x32_bf16(af[i], bfv[j], acc[i][j], 0, 0, 0);
        }
    }

    #pragma unroll
    for (int i = 0; i < 4; ++i) {
        #pragma unroll
        for (int j = 0; j < 4; ++j) {
            int r0 = row0 + wr + i * 16 + ((l >> 4) << 2);
            int c  = col0 + wc + j * 16 + (l & 15);
            #pragma unroll
            for (int r = 0; r < 4; ++r) {
                if (r0 + r < M) {
                    if (OUT_BF16)
                        ((unsigned short*)Cout)[(size_t)(r0 + r) * N + c] = f2bf(acc[i][j][r]);
                    else
                        ((float*)Cout)[(size_t)(r0 + r) * N + c] = acc[i][j][r];
                }
            }
        }
    }
}

// ---------------- gather-aggregate + combine, layer 1 (bf16 in/out, relu) ----
__global__ __launch_bounds__(256) void agg_combine256(
    const unsigned short* __restrict__ C1, const int* __restrict__ off, const int* __restrict__ eidx,
    const float* __restrict__ b, unsigned short* __restrict__ h1b)
{
    const int wave = threadIdx.x >> 6, lane = threadIdx.x & 63;
    const int n = blockIdx.x * 4 + wave;
    if (n >= NN) return;
    const int e0 = off[n], e1 = off[n + 1];
    float acc0 = 0.f, acc1 = 0.f, acc2 = 0.f, acc3 = 0.f;
    for (int e = e0; e < e1; ++e) {
        int s = eidx[e];
        ushort4 v = *(const ushort4*)&C1[(size_t)s * 512 + 256 + lane * 4];
        acc0 += bf2f(v.x); acc1 += bf2f(v.y); acc2 += bf2f(v.z); acc3 += bf2f(v.w);
    }
    const float rd = (e1 > e0) ? 1.0f / (float)(e1 - e0) : 1.0f;
    ushort4 sv = *(const ushort4*)&C1[(size_t)n * 512 + lane * 4];
    float4 bb = ((const float4*)b)[lane];
    ushort4 o;
    o.x = f2bf(fmaxf(bf2f(sv.x) + acc0 * rd + bb.x, 0.f));
    o.y = f2bf(fmaxf(bf2f(sv.y) + acc1 * rd + bb.y, 0.f));
    o.z = f2bf(fmaxf(bf2f(sv.z) + acc2 * rd + bb.z, 0.f));
    o.w = f2bf(fmaxf(bf2f(sv.w) + acc3 * rd + bb.w, 0.f));
    *(ushort4*)&h1b[(size_t)n * 256 + lane * 4] = o;
}

// ---------------- gather-aggregate + combine, layer 2 (fp32 in, bf16 out) ----
__global__ __launch_bounds__(256) void agg_combine64(
    const float* __restrict__ C2, const int* __restrict__ off, const int* __restrict__ eidx,
    const float* __restrict__ b, unsigned short* __restrict__ h2b)
{
    const int wave = threadIdx.x >> 6, lane = threadIdx.x & 63;
    const int n = blockIdx.x * 4 + wave;
    if (n >= NN) return;
    const int e0 = off[n], e1 = off[n + 1];
    float acc = 0.f;
    for (int e = e0; e < e1; ++e) {
        int s = eidx[e];
        acc += C2[(size_t)s * 128 + 64 + lane];
    }
    const float rd = (e1 > e0) ? 1.0f / (float)(e1 - e0) : 1.0f;
    h2b[(size_t)n * 64 + lane] = f2bf(C2[(size_t)n * 128 + lane] + acc * rd + b[lane]);
}

// ---------------- edge MLP via MFMA ----------------
// 128 edges/block, 4 waves. Z[128][128] bf16 in LDS (XOR-swizzled),
// Wp1b[64 cols][128 k] bf16 loaded to regs from L2. Wave w computes rows w*32..w*32+31.
__global__ __launch_bounds__(256) void edge_mlp_mfma(
    const unsigned short* __restrict__ h2b,
    const int* __restrict__ psrc, const int* __restrict__ pdst,
    const int* __restrict__ nsrc, const int* __restrict__ ndst,
    const unsigned short* __restrict__ Wp1b, const float* __restrict__ bp1,
    const float* __restrict__ Wp2, const float* __restrict__ bp2,
    float* __restrict__ out)
{
    __shared__ unsigned short z[128 * 128];   // [row][chunk^ (row&15)] chunks of 8 bf16
    const int tid = threadIdx.x;
    const int w = tid >> 6, l = tid & 63;
    const int e0 = blockIdx.x * 128;

    // B fragments: bfr[kk][j], col = j*16+(l&15), k-chunk = kk*4+(l>>4)
    bf16x8 bfr[4][4];
    #pragma unroll
    for (int kk = 0; kk < 4; ++kk)
        #pragma unroll
        for (int j = 0; j < 4; ++j) {
            int col = j * 16 + (l & 15);
            int ch  = kk * 4 + (l >> 4);
            bfr[kk][j] = *(const bf16x8*)(Wp1b + col * 128 + ch * 8);
        }

    // gather 256 node-rows (128 edges x {src,dst}), 8 threads per row
    #pragma unroll
    for (int p = 0; p < 8; ++p) {
        int rho = p * 32 + (tid >> 3);        // 0..255
        int c   = tid & 7;                    // 16B chunk within 128B half-row
        int r   = rho >> 1;                   // edge row in block
        int ep  = rho & 1;                    // 0=src endpoint, 1=dst endpoint
        int e   = e0 + r; if (e >= 2 * NP) e = 2 * NP - 1;
        int node = (e < NP) ? (ep ? pdst[e] : psrc[e])
                            : (ep ? ndst[e - NP] : nsrc[e - NP]);
        bf16x8 v = *(const bf16x8*)(h2b + (size_t)node * 64 + c * 8);
        int j = ep * 8 + c;                   // chunk 0..15 within z row
        *(bf16x8*)&z[r * 128 + ((j ^ (r & 15)) * 8)] = v;
    }
    __syncthreads();

    f32x4 acc[2][4];
    #pragma unroll
    for (int i = 0; i < 2; ++i)
        #pragma unroll
        for (int j = 0; j < 4; ++j)
            #pragma unroll
            for (int r = 0; r < 4; ++r) acc[i][j][r] = 0.0f;

    #pragma unroll
    for (int kk = 0; kk < 4; ++kk) {
        bf16x8 af[2];
        #pragma unroll
        for (int i = 0; i < 2; ++i) {
            int row = w * 32 + i * 16 + (l & 15);
            int ch  = (kk * 4 + (l >> 4)) ^ (row & 15);
            af[i] = *(const bf16x8*)&z[row * 128 + ch * 8];
        }
        #pragma unroll
        for (int i = 0; i < 2; ++i)
            #pragma unroll
            for (int j = 0; j < 4; ++j)
                acc[i][j] = __builtin_amdgcn_mfma_f32_16x16x32_bf16(af[i], bfr[kk][j], acc[i][j], 0, 0, 0);
    }

    // epilogue: relu + Wp2 dot + reduce across 16 cols
    float bp1v[4], w2v[4];
    #pragma unroll
    for (int j = 0; j < 4; ++j) {
        bp1v[j] = bp1[j * 16 + (l & 15)];
        w2v[j]  = Wp2[j * 16 + (l & 15)];
    }
    const float b2v = bp2[0];
    #pragma unroll
    for (int i = 0; i < 2; ++i) {
        #pragma unroll
        for (int r = 0; r < 4; ++r) {
            float p = 0.f;
            #pragma unroll
            for (int j = 0; j < 4; ++j) {
                float h = fmaxf(acc[i][j][r] + bp1v[j], 0.f);
                p = fmaf(h, w2v[j], p);
            }
            #pragma unroll
            for (int off = 8; off > 0; off >>= 1)
                p += __shfl_xor(p, off, 64);
            int row = w * 32 + i * 16 + ((l >> 4) << 2) + r;
            if ((l & 15) == 0 && e0 + row < 2 * NP)
                out[e0 + row] = p + b2v;
        }
    }
}

extern "C" void kernel_launch(void* const* d_in, const int* in_sizes, int n_in,
                              void* d_out, int out_size, void* d_ws, size_t ws_size,
                              hipStream_t stream) {
    (void)in_sizes; (void)n_in; (void)out_size; (void)ws_size;
    const float* x       = (const float*)d_in[0];
    const int*   esrc    = (const int*)d_in[1];
    const int*   edst    = (const int*)d_in[2];
    const int*   psrc    = (const int*)d_in[3];
    const int*   pdst    = (const int*)d_in[4];
    const int*   nsrc    = (const int*)d_in[5];
    const int*   ndst    = (const int*)d_in[6];
    const float* Wself1  = (const float*)d_in[7];
    const float* Wneigh1 = (const float*)d_in[8];
    const float* b1      = (const float*)d_in[9];
    const float* Wself2  = (const float*)d_in[10];
    const float* Wneigh2 = (const float*)d_in[11];
    const float* b2      = (const float*)d_in[12];
    const float* Wp1     = (const float*)d_in[13];
    const float* bp1     = (const float*)d_in[14];
    const float* Wp2     = (const float*)d_in[15];
    const float* bp2     = (const float*)d_in[16];
    float* out = (float*)d_out;

    // -------- workspace carve-up --------
    char* w = (char*)d_ws;
    int* deg_i  = (int*)w; w += 50048 * 4;
    int* off    = (int*)w; w += 50052 * 4;
    int* cursor = (int*)w; w += 50048 * 4;
    int* bsums  = (int*)w; w += 256 * 4;
    int* boff   = (int*)w; w += 256 * 4;
    int* eidx   = (int*)w; w += 160000 * 4;
    unsigned short* Bt1  = (unsigned short*)w; w += (size_t)512 * 512 * 2;
    unsigned short* Bt2  = (unsigned short*)w; w += (size_t)128 * 256 * 2;
    unsigned short* Wp1b = (unsigned short*)w; w += (size_t)64 * 128 * 2;
    unsigned short* xb   = (unsigned short*)w; w += (size_t)NN * DIN * 2;  // 51.2 MB
    unsigned short* C1b  = (unsigned short*)w; w += (size_t)NN * 512 * 2;  // 51.2 MB
    unsigned short* h1b = xb;                                   // 25.6 MB (xb dead after GEMM1)
    unsigned short* h2b = xb + (size_t)NN * DH;                 // 6.4 MB
    float* C2 = (float*)C1b;                                    // 25.6 MB (C1b dead after agg1)

    // -------- CSR build --------
    hipMemsetAsync(deg_i, 0, 50048 * 4, stream);
    deg_count<<<(NE + 255) / 256, 256, 0, stream>>>(edst, deg_i);
    scan_part<<<NBLK_SCAN, 256, 0, stream>>>(deg_i, off, bsums);
    scan_sums<<<1, 256, 0, stream>>>(bsums, boff);
    scan_add<<<NBLK_SCAN, 256, 0, stream>>>(off, boff, cursor);
    fill_csr<<<(NE + 255) / 256, 256, 0, stream>>>(esrc, edst, cursor, eidx);

    // -------- prep conversions --------
    cvt_x_kernel<<<(NN * DIN / 4 + 255) / 256, 256, 0, stream>>>(x, xb);
    prep_w<<<(512 * 512 + 255) / 256, 256, 0, stream>>>(Wself1, Wneigh1, Bt1, DIN, DH);
    prep_w<<<(128 * 256 + 255) / 256, 256, 0, stream>>>(Wself2, Wneigh2, Bt2, DH, DO);
    prep_wp1<<<(64 * 128 + 255) / 256, 256, 0, stream>>>(Wp1, Wp1b);

    // -------- layer 1 --------
    dim3 g1(512 / 128, (NN + 127) / 128);     // (4, 391)
    gemm_bf16<true><<<g1, 256, 0, stream>>>(xb, Bt1, C1b, NN, 512, DIN);
    agg_combine256<<<(NN + 3) / 4, 256, 0, stream>>>(C1b, off, eidx, b1, h1b);

    // -------- layer 2 --------
    dim3 g2(1, (NN + 127) / 128);             // (1, 391)
    gemm_bf16<false><<<g2, 256, 0, stream>>>(h1b, Bt2, C2, NN, 128, DH);
    agg_combine64<<<(NN + 3) / 4, 256, 0, stream>>>(C2, off, eidx, b2, h2b);

    // -------- edge scorer (MFMA) --------
    edge_mlp_mfma<<<(2 * NP + 127) / 128, 256, 0, stream>>>(h2b, psrc, pdst, nsrc, ndst,
                                                            Wp1b, bp1, Wp2, bp2, out);
}

// Round 5
// 206.316 us; speedup vs baseline: 6.6692x; 1.0478x over previous
//
#include <hip/hip_runtime.h>

#define NN 50000      // nodes
#define NE 160000     // graph edges
#define NP 100000     // pos (=neg) edges
#define DIN 512
#define DH  256
#define DO  64
#define NBLK_SCAN 196 // ceil(50000/256)

typedef short bf16x8 __attribute__((ext_vector_type(8)));
typedef float f32x4  __attribute__((ext_vector_type(4)));

__device__ __forceinline__ float bf2f(unsigned short u) {
    return __uint_as_float(((unsigned int)u) << 16);
}
__device__ __forceinline__ unsigned short f2bf(float f) {
    unsigned int x = __float_as_uint(f);
    return (unsigned short)((x + 0x7fffu + ((x >> 16) & 1u)) >> 16);
}

__device__ __forceinline__ void gload_lds16(const void* g, void* l) {
    __builtin_amdgcn_global_load_lds(
        (const __attribute__((address_space(1))) void*)g,
        (__attribute__((address_space(3))) void*)l, 16, 0, 0);
}

// ---------------- CSR build ----------------
__global__ __launch_bounds__(256) void deg_count(const int* __restrict__ dst, int* __restrict__ deg) {
    int e = blockIdx.x * 256 + threadIdx.x;
    if (e < NE) atomicAdd(&deg[dst[e]], 1);
}

__global__ __launch_bounds__(256) void scan_part(const int* __restrict__ deg, int* __restrict__ excl,
                                                 int* __restrict__ bsums) {
    __shared__ int sh[256];
    int i = blockIdx.x * 256 + threadIdx.x;
    int v = (i < NN) ? deg[i] : 0;
    sh[threadIdx.x] = v;
    __syncthreads();
    #pragma unroll
    for (int off = 1; off < 256; off <<= 1) {
        int t = (threadIdx.x >= off) ? sh[threadIdx.x - off] : 0;
        __syncthreads();
        sh[threadIdx.x] += t;
        __syncthreads();
    }
    if (i < NN) excl[i] = sh[threadIdx.x] - v;
    if (threadIdx.x == 255) bsums[blockIdx.x] = sh[255];
}

__global__ __launch_bounds__(256) void scan_sums(int* __restrict__ bsums, int* __restrict__ boff) {
    __shared__ int sh[256];
    int v = (threadIdx.x < NBLK_SCAN) ? bsums[threadIdx.x] : 0;
    sh[threadIdx.x] = v;
    __syncthreads();
    #pragma unroll
    for (int off = 1; off < 256; off <<= 1) {
        int t = (threadIdx.x >= off) ? sh[threadIdx.x - off] : 0;
        __syncthreads();
        sh[threadIdx.x] += t;
        __syncthreads();
    }
    boff[threadIdx.x] = sh[threadIdx.x] - v;
}

__global__ __launch_bounds__(256) void scan_add(int* __restrict__ off, const int* __restrict__ boff,
                                                int* __restrict__ cursor) {
    int i = blockIdx.x * 256 + threadIdx.x;
    if (i < NN) {
        int o = off[i] + boff[blockIdx.x];
        off[i] = o;
        cursor[i] = o;
    }
    if (i == 0) off[NN] = NE;
}

__global__ __launch_bounds__(256) void fill_csr(const int* __restrict__ src, const int* __restrict__ dst,
                                                int* __restrict__ cursor, int* __restrict__ eidx) {
    int e = blockIdx.x * 256 + threadIdx.x;
    if (e < NE) {
        int p = atomicAdd(&cursor[dst[e]], 1);
        eidx[p] = src[e];
    }
}

// ---------------- prep: weights fp32 -> bf16 ----------------
// Bt[n][k] = W(k, n) for concatenated [W_self | W_neigh], bf16 out
__global__ __launch_bounds__(256) void prep_w(const float* __restrict__ Wself, const float* __restrict__ Wneigh,
                                              unsigned short* __restrict__ Bt, int K, int Nhalf) {
    int idx = blockIdx.x * 256 + threadIdx.x;
    int N = 2 * Nhalf;
    if (idx >= N * K) return;
    int n = idx / K, k = idx - n * K;
    float v = (n < Nhalf) ? Wself[(size_t)k * Nhalf + n] : Wneigh[(size_t)k * Nhalf + (n - Nhalf)];
    Bt[idx] = f2bf(v);
}

// Wp1b[n][k] = Wp1[k][n], bf16 (n<64, k<128)
__global__ __launch_bounds__(256) void prep_wp1(const float* __restrict__ Wp1, unsigned short* __restrict__ Wp1b) {
    int idx = blockIdx.x * 256 + threadIdx.x;
    if (idx >= 64 * 128) return;
    int n = idx >> 7, k = idx & 127;
    Wp1b[idx] = f2bf(Wp1[(size_t)k * 64 + n]);
}

// ---------------- layer-1 GEMM: C[M,N] = cvt_bf16(A_f32[M,K]) @ Bt[N,K]^T ------
// BM=BN=128, BK=64, 4 waves. A reg-staged fp32->bf16 with XOR-swizzled ds_write;
// B via global_load_lds (pre-swizzled source). 1D grid + bijective XCD-chunk swizzle.
__global__ __launch_bounds__(256) void gemm_f32a(
    const float* __restrict__ A, const unsigned short* __restrict__ Bt,
    unsigned short* __restrict__ Cout, int M, int N, int K)
{
    __shared__ unsigned short As[128 * 64];
    __shared__ unsigned short Bs[128 * 64];
    const int tid = threadIdx.x;
    const int w = tid >> 6, l = tid & 63;
    const int wr = (w >> 1) * 64, wc = (w & 1) * 64;

    // bijective XCD-chunk swizzle (m204): works ordered y-major so the gx
    // column-blocks of one row-panel are consecutive -> same XCD -> A in L2
    const int nwg = gridDim.x, gx = N >> 7;
    const int q = nwg >> 3, r = nwg & 7;
    const int xcd = blockIdx.x & 7, pos = blockIdx.x >> 3;
    const int work = (xcd < r ? xcd * (q + 1) : r * (q + 1) + (xcd - r) * q) + pos;
    const int row0 = (work / gx) * 128, col0 = (work % gx) * 128;

    f32x4 acc[4][4];
    #pragma unroll
    for (int i = 0; i < 4; ++i)
        #pragma unroll
        for (int j = 0; j < 4; ++j)
            #pragma unroll
            for (int rr = 0; rr < 4; ++rr) acc[i][j][rr] = 0.0f;

    const int wave_lds_chunk = (tid & 192) * 8;

    for (int k0 = 0; k0 < K; k0 += 64) {
        __syncthreads();
        // B tile: async global->LDS, source pre-swizzled, dest linear
        #pragma unroll
        for (int u = 0; u < 4; ++u) {
            int c = u * 256 + tid;
            int cn = c >> 3, j = c & 7;
            int js = j ^ (cn & 7);
            gload_lds16(Bt + (size_t)(col0 + cn) * K + k0 + js * 8,
                        (void*)(Bs + (u * 256) * 8 + wave_lds_chunk));
        }
        // A tile: reg-stage fp32 (coalesced 32B/lane), cvt to bf16, swizzled ds_write
        #pragma unroll
        for (int u = 0; u < 4; ++u) {
            int c = u * 256 + tid;
            int row = c >> 3, j = c & 7;
            int grow = row0 + row; if (grow >= M) grow = M - 1;
            const float* src = A + (size_t)grow * K + k0 + j * 8;
            float4 v0 = *(const float4*)src;
            float4 v1 = *(const float4*)(src + 4);
            union { bf16x8 v; unsigned short u16[8]; } pk;
            pk.u16[0] = f2bf(v0.x); pk.u16[1] = f2bf(v0.y);
            pk.u16[2] = f2bf(v0.z); pk.u16[3] = f2bf(v0.w);
            pk.u16[4] = f2bf(v1.x); pk.u16[5] = f2bf(v1.y);
            pk.u16[6] = f2bf(v1.z); pk.u16[7] = f2bf(v1.w);
            int js = j ^ (row & 7);
            *(bf16x8*)&As[row * 64 + js * 8] = pk.v;
        }
        __syncthreads();

        #pragma unroll
        for (int kk = 0; kk < 2; ++kk) {
            bf16x8 af[4], bfv[4];
            #pragma unroll
            for (int i = 0; i < 4; ++i) {
                int row = wr + i * 16 + (l & 15);
                int ch = (kk * 4 + (l >> 4)) ^ (row & 7);
                af[i] = *(const bf16x8*)&As[row * 64 + ch * 8];
            }
            #pragma unroll
            for (int j = 0; j < 4; ++j) {
                int cc = wc + j * 16 + (l & 15);
                int ch = (kk * 4 + (l >> 4)) ^ (cc & 7);
                bfv[j] = *(const bf16x8*)&Bs[cc * 64 + ch * 8];
            }
            #pragma unroll
            for (int i = 0; i < 4; ++i)
                #pragma unroll
                for (int j = 0; j < 4; ++j)
                    acc[i][j] = __builtin_amdgcn_mfma_f32_16x16x32_bf16(af[i], bfv[j], acc[i][j], 0, 0, 0);
        }
    }

    #pragma unroll
    for (int i = 0; i < 4; ++i) {
        #pragma unroll
        for (int j = 0; j < 4; ++j) {
            int r0 = row0 + wr + i * 16 + ((l >> 4) << 2);
            int c  = col0 + wc + j * 16 + (l & 15);
            #pragma unroll
            for (int rr = 0; rr < 4; ++rr) {
                if (r0 + rr < M)
                    Cout[(size_t)(r0 + rr) * N + c] = f2bf(acc[i][j][rr]);
            }
        }
    }
}

// ---------------- layer-2 GEMM: bf16 A, bf16 Bt, fp32 out ----------------
__global__ __launch_bounds__(256) void gemm_bf16(
    const unsigned short* __restrict__ A, const unsigned short* __restrict__ Bt,
    float* __restrict__ Cout, int M, int N, int K)
{
    __shared__ unsigned short As[128 * 64];
    __shared__ unsigned short Bs[128 * 64];
    const int tid = threadIdx.x;
    const int w = tid >> 6, l = tid & 63;
    const int wr = (w >> 1) * 64, wc = (w & 1) * 64;
    const int row0 = blockIdx.y * 128, col0 = blockIdx.x * 128;

    f32x4 acc[4][4];
    #pragma unroll
    for (int i = 0; i < 4; ++i)
        #pragma unroll
        for (int j = 0; j < 4; ++j)
            #pragma unroll
            for (int rr = 0; rr < 4; ++rr) acc[i][j][rr] = 0.0f;

    const int wave_lds_chunk = (tid & 192) * 8;

    for (int k0 = 0; k0 < K; k0 += 64) {
        __syncthreads();
        #pragma unroll
        for (int u = 0; u < 4; ++u) {
            int c = u * 256 + tid;
            int row = c >> 3, j = c & 7;
            int js = j ^ (row & 7);
            int grow = row0 + row; if (grow >= M) grow = M - 1;
            gload_lds16(A + (size_t)grow * K + k0 + js * 8,
                        (void*)(As + (u * 256) * 8 + wave_lds_chunk));
        }
        #pragma unroll
        for (int u = 0; u < 4; ++u) {
            int c = u * 256 + tid;
            int cn = c >> 3, j = c & 7;
            int js = j ^ (cn & 7);
            gload_lds16(Bt + (size_t)(col0 + cn) * K + k0 + js * 8,
                        (void*)(Bs + (u * 256) * 8 + wave_lds_chunk));
        }
        __syncthreads();

        #pragma unroll
        for (int kk = 0; kk < 2; ++kk) {
            bf16x8 af[4], bfv[4];
            #pragma unroll
            for (int i = 0; i < 4; ++i) {
                int row = wr + i * 16 + (l & 15);
                int ch = (kk * 4 + (l >> 4)) ^ (row & 7);
                af[i] = *(const bf16x8*)&As[row * 64 + ch * 8];
            }
            #pragma unroll
            for (int j = 0; j < 4; ++j) {
                int cc = wc + j * 16 + (l & 15);
                int ch = (kk * 4 + (l >> 4)) ^ (cc & 7);
                bfv[j] = *(const bf16x8*)&Bs[cc * 64 + ch * 8];
            }
            #pragma unroll
            for (int i = 0; i < 4; ++i)
                #pragma unroll
                for (int j = 0; j < 4; ++j)
                    acc[i][j] = __builtin_amdgcn_mfma_f32_16x16x32_bf16(af[i], bfv[j], acc[i][j], 0, 0, 0);
        }
    }

    #pragma unroll
    for (int i = 0; i < 4; ++i) {
        #pragma unroll
        for (int j = 0; j < 4; ++j) {
            int r0 = row0 + wr + i * 16 + ((l >> 4) << 2);
            int c  = col0 + wc + j * 16 + (l & 15);
            #pragma unroll
            for (int rr = 0; rr < 4; ++rr) {
                if (r0 + rr < M)
                    Cout[(size_t)(r0 + rr) * N + c] = acc[i][j][rr];
            }
        }
    }
}

// ---------------- gather-aggregate + combine, layer 1 (bf16 in/out, relu) ----
__global__ __launch_bounds__(256) void agg_combine256(
    const unsigned short* __restrict__ C1, const int* __restrict__ off, const int* __restrict__ eidx,
    const float* __restrict__ b, unsigned short* __restrict__ h1b)
{
    const int wave = threadIdx.x >> 6, lane = threadIdx.x & 63;
    const int n = blockIdx.x * 4 + wave;
    if (n >= NN) return;
    const int e0 = off[n], e1 = off[n + 1];
    float acc0 = 0.f, acc1 = 0.f, acc2 = 0.f, acc3 = 0.f;
    for (int e = e0; e < e1; ++e) {
        int s = eidx[e];
        ushort4 v = *(const ushort4*)&C1[(size_t)s * 512 + 256 + lane * 4];
        acc0 += bf2f(v.x); acc1 += bf2f(v.y); acc2 += bf2f(v.z); acc3 += bf2f(v.w);
    }
    const float rd = (e1 > e0) ? 1.0f / (float)(e1 - e0) : 1.0f;
    ushort4 sv = *(const ushort4*)&C1[(size_t)n * 512 + lane * 4];
    float4 bb = ((const float4*)b)[lane];
    ushort4 o;
    o.x = f2bf(fmaxf(bf2f(sv.x) + acc0 * rd + bb.x, 0.f));
    o.y = f2bf(fmaxf(bf2f(sv.y) + acc1 * rd + bb.y, 0.f));
    o.z = f2bf(fmaxf(bf2f(sv.z) + acc2 * rd + bb.z, 0.f));
    o.w = f2bf(fmaxf(bf2f(sv.w) + acc3 * rd + bb.w, 0.f));
    *(ushort4*)&h1b[(size_t)n * 256 + lane * 4] = o;
}

// ---------------- gather-aggregate + combine, layer 2 (fp32 in, bf16 out) ----
__global__ __launch_bounds__(256) void agg_combine64(
    const float* __restrict__ C2, const int* __restrict__ off, const int* __restrict__ eidx,
    const float* __restrict__ b, unsigned short* __restrict__ h2b)
{
    const int wave = threadIdx.x >> 6, lane = threadIdx.x & 63;
    const int n = blockIdx.x * 4 + wave;
    if (n >= NN) return;
    const int e0 = off[n], e1 = off[n + 1];
    float acc = 0.f;
    for (int e = e0; e < e1; ++e) {
        int s = eidx[e];
        acc += C2[(size_t)s * 128 + 64 + lane];
    }
    const float rd = (e1 > e0) ? 1.0f / (float)(e1 - e0) : 1.0f;
    h2b[(size_t)n * 64 + lane] = f2bf(C2[(size_t)n * 128 + lane] + acc * rd + b[lane]);
}

// ---------------- edge MLP via MFMA ----------------
__global__ __launch_bounds__(256) void edge_mlp_mfma(
    const unsigned short* __restrict__ h2b,
    const int* __restrict__ psrc, const int* __restrict__ pdst,
    const int* __restrict__ nsrc, const int* __restrict__ ndst,
    const unsigned short* __restrict__ Wp1b, const float* __restrict__ bp1,
    const float* __restrict__ Wp2, const float* __restrict__ bp2,
    float* __restrict__ out)
{
    __shared__ unsigned short z[128 * 128];
    const int tid = threadIdx.x;
    const int w = tid >> 6, l = tid & 63;
    const int e0 = blockIdx.x * 128;

    bf16x8 bfr[4][4];
    #pragma unroll
    for (int kk = 0; kk < 4; ++kk)
        #pragma unroll
        for (int j = 0; j < 4; ++j) {
            int col = j * 16 + (l & 15);
            int ch  = kk * 4 + (l >> 4);
            bfr[kk][j] = *(const bf16x8*)(Wp1b + col * 128 + ch * 8);
        }

    #pragma unroll
    for (int p = 0; p < 8; ++p) {
        int rho = p * 32 + (tid >> 3);
        int c   = tid & 7;
        int r   = rho >> 1;
        int ep  = rho & 1;
        int e   = e0 + r; if (e >= 2 * NP) e = 2 * NP - 1;
        int node = (e < NP) ? (ep ? pdst[e] : psrc[e])
                            : (ep ? ndst[e - NP] : nsrc[e - NP]);
        bf16x8 v = *(const bf16x8*)(h2b + (size_t)node * 64 + c * 8);
        int j = ep * 8 + c;
        *(bf16x8*)&z[r * 128 + ((j ^ (r & 15)) * 8)] = v;
    }
    __syncthreads();

    f32x4 acc[2][4];
    #pragma unroll
    for (int i = 0; i < 2; ++i)
        #pragma unroll
        for (int j = 0; j < 4; ++j)
            #pragma unroll
            for (int rr = 0; rr < 4; ++rr) acc[i][j][rr] = 0.0f;

    #pragma unroll
    for (int kk = 0; kk < 4; ++kk) {
        bf16x8 af[2];
        #pragma unroll
        for (int i = 0; i < 2; ++i) {
            int row = w * 32 + i * 16 + (l & 15);
            int ch  = (kk * 4 + (l >> 4)) ^ (row & 15);
            af[i] = *(const bf16x8*)&z[row * 128 + ch * 8];
        }
        #pragma unroll
        for (int i = 0; i < 2; ++i)
            #pragma unroll
            for (int j = 0; j < 4; ++j)
                acc[i][j] = __builtin_amdgcn_mfma_f32_16x16x32_bf16(af[i], bfr[kk][j], acc[i][j], 0, 0, 0);
    }

    float bp1v[4], w2v[4];
    #pragma unroll
    for (int j = 0; j < 4; ++j) {
        bp1v[j] = bp1[j * 16 + (l & 15)];
        w2v[j]  = Wp2[j * 16 + (l & 15)];
    }
    const float b2v = bp2[0];
    #pragma unroll
    for (int i = 0; i < 2; ++i) {
        #pragma unroll
        for (int rr = 0; rr < 4; ++rr) {
            float p = 0.f;
            #pragma unroll
            for (int j = 0; j < 4; ++j) {
                float h = fmaxf(acc[i][j][rr] + bp1v[j], 0.f);
                p = fmaf(h, w2v[j], p);
            }
            #pragma unroll
            for (int off = 8; off > 0; off >>= 1)
                p += __shfl_xor(p, off, 64);
            int row = w * 32 + i * 16 + ((l >> 4) << 2) + rr;
            if ((l & 15) == 0 && e0 + row < 2 * NP)
                out[e0 + row] = p + b2v;
        }
    }
}

extern "C" void kernel_launch(void* const* d_in, const int* in_sizes, int n_in,
                              void* d_out, int out_size, void* d_ws, size_t ws_size,
                              hipStream_t stream) {
    (void)in_sizes; (void)n_in; (void)out_size; (void)ws_size;
    const float* x       = (const float*)d_in[0];
    const int*   esrc    = (const int*)d_in[1];
    const int*   edst    = (const int*)d_in[2];
    const int*   psrc    = (const int*)d_in[3];
    const int*   pdst    = (const int*)d_in[4];
    const int*   nsrc    = (const int*)d_in[5];
    const int*   ndst    = (const int*)d_in[6];
    const float* Wself1  = (const float*)d_in[7];
    const float* Wneigh1 = (const float*)d_in[8];
    const float* b1      = (const float*)d_in[9];
    const float* Wself2  = (const float*)d_in[10];
    const float* Wneigh2 = (const float*)d_in[11];
    const float* b2      = (const float*)d_in[12];
    const float* Wp1     = (const float*)d_in[13];
    const float* bp1     = (const float*)d_in[14];
    const float* Wp2     = (const float*)d_in[15];
    const float* bp2     = (const float*)d_in[16];
    float* out = (float*)d_out;

    // -------- workspace carve-up --------
    char* w = (char*)d_ws;
    int* deg_i  = (int*)w; w += 50048 * 4;
    int* off    = (int*)w; w += 50052 * 4;
    int* cursor = (int*)w; w += 50048 * 4;
    int* bsums  = (int*)w; w += 256 * 4;
    int* boff   = (int*)w; w += 256 * 4;
    int* eidx   = (int*)w; w += 160000 * 4;
    unsigned short* Bt1  = (unsigned short*)w; w += (size_t)512 * 512 * 2;
    unsigned short* Bt2  = (unsigned short*)w; w += (size_t)128 * 256 * 2;
    unsigned short* Wp1b = (unsigned short*)w; w += (size_t)64 * 128 * 2;
    unsigned short* h1b  = (unsigned short*)w; w += (size_t)NN * DH * 2;   // 25.6 MB
    unsigned short* h2b  = (unsigned short*)w; w += (size_t)NN * DO * 2;   // 6.4 MB
    unsigned short* C1b  = (unsigned short*)w; w += (size_t)NN * 512 * 2;  // 51.2 MB
    float* C2 = (float*)C1b;   // C1b dead after agg1; C2 = 25.6 MB fp32

    // -------- CSR build --------
    hipMemsetAsync(deg_i, 0, 50048 * 4, stream);
    deg_count<<<(NE + 255) / 256, 256, 0, stream>>>(edst, deg_i);
    scan_part<<<NBLK_SCAN, 256, 0, stream>>>(deg_i, off, bsums);
    scan_sums<<<1, 256, 0, stream>>>(bsums, boff);
    scan_add<<<NBLK_SCAN, 256, 0, stream>>>(off, boff, cursor);
    fill_csr<<<(NE + 255) / 256, 256, 0, stream>>>(esrc, edst, cursor, eidx);

    // -------- prep conversions (weights only) --------
    prep_w<<<(512 * 512 + 255) / 256, 256, 0, stream>>>(Wself1, Wneigh1, Bt1, DIN, DH);
    prep_w<<<(128 * 256 + 255) / 256, 256, 0, stream>>>(Wself2, Wneigh2, Bt2, DH, DO);
    prep_wp1<<<(64 * 128 + 255) / 256, 256, 0, stream>>>(Wp1, Wp1b);

    // -------- layer 1: fused cvt+GEMM (1D grid, XCD-chunk swizzle) --------
    int nwg1 = (512 / 128) * ((NN + 127) / 128);   // 4 * 391 = 1564
    gemm_f32a<<<nwg1, 256, 0, stream>>>(x, Bt1, C1b, NN, 512, DIN);
    agg_combine256<<<(NN + 3) / 4, 256, 0, stream>>>(C1b, off, eidx, b1, h1b);

    // -------- layer 2 --------
    dim3 g2(1, (NN + 127) / 128);                  // (1, 391)
    gemm_bf16<<<g2, 256, 0, stream>>>(h1b, Bt2, C2, NN, 128, DH);
    agg_combine64<<<(NN + 3) / 4, 256, 0, stream>>>(C2, off, eidx, b2, h2b);

    // -------- edge scorer (MFMA) --------
    edge_mlp_mfma<<<(2 * NP + 127) / 128, 256, 0, stream>>>(h2b, psrc, pdst, nsrc, ndst,
                                                            Wp1b, bp1, Wp2, bp2, out);
}